// Round 3
// baseline (853.875 us; speedup 1.0000x reference)
//
#include <hip/hip_runtime.h>
#include <hip/hip_bf16.h>

// Problem: b=8, n=25, t=64, C=512, PC=128, heads=8, d=16
// Inputs fp32 (bf16-rounded values), output fp32 buffer; harness threshold ~9.75e-2.
#define SCALE 0.25f           // d^-0.5, d=16
#define BUF   1638400ull      // 12800 tokens * 128 ch (one q/k/v/ob buffer)

// ---------------------------------------------------------------------------
// Kernel 1: QKV projection for ONE branch.
// grid = 800 blocks (16 tokens each), block = 384 threads (1 per out col).
// Output layout: buf[((batch*8 + h)*N + seq)*16 + dd]  (attention-friendly)
//   br=0 (t):  batch=(b*25+n) [200], seq=t,        N=64
//   br=1 (s):  batch=b*64+t   [512], seq=n,        N=25
//   br=2 (st): batch=b        [8],   seq=n*64+t,   N=1600
// ---------------------------------------------------------------------------
__global__ __launch_bounds__(384) void qkv_proj(
    const float* __restrict__ x, const float* __restrict__ w,
    const float* __restrict__ bias, int br, int off,
    float* __restrict__ qb, float* __restrict__ kb, float* __restrict__ vb)
{
    const int g0 = blockIdx.x * 16;

    __shared__ float xl[16][128];
    const int tid = threadIdx.x;
    for (int idx = tid; idx < 16 * 128; idx += 384) {
        int r = idx >> 7, k = idx & 127;
        xl[r][k] = x[(size_t)(g0 + r) * 512 + off + k];
    }
    __syncthreads();

    const int c = tid; // output column 0..383
    float acc[16];
#pragma unroll
    for (int r = 0; r < 16; r++) acc[r] = 0.f;

    for (int k = 0; k < 128; k += 4) {
        float w0 = w[(k + 0) * 384 + c];
        float w1 = w[(k + 1) * 384 + c];
        float w2 = w[(k + 2) * 384 + c];
        float w3 = w[(k + 3) * 384 + c];
#pragma unroll
        for (int r = 0; r < 16; r++) {
            float4 xv = *(const float4*)&xl[r][k];   // LDS broadcast
            acc[r] += xv.x * w0 + xv.y * w1 + xv.z * w2 + xv.w * w3;
        }
    }

    const float bv  = bias[c];
    const int which = c >> 7;          // 0=q 1=k 2=v
    const int rem   = c & 127;
    const int h     = rem >> 4;
    const int dd    = rem & 15;
    float* outbuf = (which == 0) ? qb : (which == 1) ? kb : vb;

#pragma unroll
    for (int r = 0; r < 16; r++) {
        int g = g0 + r;            // token index = (b*25+n)*64 + t
        int batch, seq, N;
        if (br == 0)      { batch = g >> 6; seq = g & 63; N = 64; }
        else if (br == 1) { int b_ = g / 1600, rm = g % 1600;
                            batch = b_ * 64 + (rm & 63); seq = rm >> 6; N = 25; }
        else              { batch = g / 1600; seq = g % 1600; N = 1600; }
        outbuf[(((size_t)batch * 8 + h) * N + seq) * 16 + dd] = acc[r] + bv;
    }
}

// ---------------------------------------------------------------------------
// Kernel 2a: attention for t (N=64, 200 batches, 512 thr) and
//            s (N=25, 512 batches, 256 thr). One block per batch.
// Writes ob[g*128 + h*16 + i], g in (b,n,t) token order.
// ---------------------------------------------------------------------------
template<int BR, int N>
__global__ __launch_bounds__(512) void attn_small(
    const float* __restrict__ qb, const float* __restrict__ kb,
    const float* __restrict__ vb, float* __restrict__ ob)
{
    const int batch = blockIdx.x;
    __shared__ float kl[8 * N * 16];
    __shared__ float vl[8 * N * 16];

    const int tid = threadIdx.x;
    const float* kg = kb + (size_t)batch * 8 * N * 16;
    const float* vg = vb + (size_t)batch * 8 * N * 16;
    for (int idx = tid; idx < 8 * N * 16; idx += blockDim.x) {
        kl[idx] = kg[idx];
        vl[idx] = vg[idx];
    }
    __syncthreads();

    const int h = tid / N, row = tid % N;
    if (h < 8) {
        const float* qrow = qb + (((size_t)batch * 8 + h) * N + row) * 16;
        float q[16];
#pragma unroll
        for (int i = 0; i < 16; i++) q[i] = qrow[i];

        float m = -1e30f, l = 0.f, o[16];
#pragma unroll
        for (int i = 0; i < 16; i++) o[i] = 0.f;

        for (int j = 0; j < N; j++) {
            const float* kj = &kl[(h * N + j) * 16];
            float s = 0.f;
#pragma unroll
            for (int i = 0; i < 16; i++) s += q[i] * kj[i];
            s *= SCALE;
            float mn   = fmaxf(m, s);
            float corr = __expf(m - mn);
            float p    = __expf(s - mn);
            l = l * corr + p;
            const float* vj = &vl[(h * N + j) * 16];
#pragma unroll
            for (int i = 0; i < 16; i++) o[i] = o[i] * corr + p * vj[i];
            m = mn;
        }

        const float inv = 1.f / l;
        int g;
        if (BR == 0) g = batch * 64 + row;                 // t: row = t
        else { int b_ = batch >> 6, t_ = batch & 63;       // s: row = n
               g = b_ * 1600 + row * 64 + t_; }
        float* orow = ob + (size_t)g * 128 + h * 16;
#pragma unroll
        for (int i = 0; i < 16; i++) orow[i] = o[i] * inv;
    }
}

// ---------------------------------------------------------------------------
// Kernel 2b: attention for st (N=1600, 8 batches x 8 heads).
// grid = 64*7 blocks (256 q-rows each); flash-style 128-row K/V chunks.
// ---------------------------------------------------------------------------
__global__ __launch_bounds__(256) void attn_st(
    const float* __restrict__ qb, const float* __restrict__ kb,
    const float* __restrict__ vb, float* __restrict__ ob)
{
    const int bid  = blockIdx.x;
    const int bh   = bid / 7;           // batch*8 + head
    const int tile = bid % 7;
    const int row  = tile * 256 + threadIdx.x;
    const bool active = (row < 1600);

    const float* kg = kb + (size_t)bh * 1600 * 16;
    const float* vg = vb + (size_t)bh * 1600 * 16;

    __shared__ float kl[128 * 16];
    __shared__ float vl[128 * 16];

    const float* qrow = qb + ((size_t)bh * 1600 + (active ? row : 0)) * 16;
    float q[16];
#pragma unroll
    for (int i = 0; i < 16; i++) q[i] = qrow[i];

    float m = -1e30f, l = 0.f, o[16];
#pragma unroll
    for (int i = 0; i < 16; i++) o[i] = 0.f;

    for (int j0 = 0; j0 < 1600; j0 += 128) {
        const int cnt = min(128, 1600 - j0);   // 12 full chunks + one of 64
        __syncthreads();
        for (int idx = threadIdx.x; idx < cnt * 16; idx += 256) {
            kl[idx] = kg[(size_t)j0 * 16 + idx];
            vl[idx] = vg[(size_t)j0 * 16 + idx];
        }
        __syncthreads();

        for (int j = 0; j < cnt; j++) {
            const float* kj = &kl[j * 16];
            float s = 0.f;
#pragma unroll
            for (int i = 0; i < 16; i++) s += q[i] * kj[i];
            s *= SCALE;
            float mn   = fmaxf(m, s);
            float corr = __expf(m - mn);
            float p    = __expf(s - mn);
            l = l * corr + p;
            const float* vj = &vl[j * 16];
#pragma unroll
            for (int i = 0; i < 16; i++) o[i] = o[i] * corr + p * vj[i];
            m = mn;
        }
    }

    if (active) {
        const float inv = 1.f / l;
        const int batch = bh >> 3, h = bh & 7;
        const int g = batch * 1600 + row;      // row = n*64 + t
        float* orow = ob + (size_t)g * 128 + h * 16;
#pragma unroll
        for (int i = 0; i < 16; i++) orow[i] = o[i] * inv;
    }
}

// ---------------------------------------------------------------------------
// Kernel 3: output projection + bias + concat/transpose/channel-shuffle store.
// One branch per launch. grid = 200 (64 t-tokens each), block = 256.
// Final mapping: out[b, c2*4+grp, n, t] = proj_row(token=(b,n,t))[c2]
// ---------------------------------------------------------------------------
__global__ __launch_bounds__(256) void proj_out(
    const float* __restrict__ ob_, const float* __restrict__ wp,
    const float* __restrict__ bp, int grp, float* __restrict__ out)
{
    const int tile = blockIdx.x;         // = (b*25+n)
    const float* ob = ob_ + (size_t)tile * 64 * 128;

    __shared__ float ol[64][128];        // 32 KB input tile
    __shared__ float res[64][128];       // 32 KB result (rotated columns)

    const int tid = threadIdx.x;
    for (int idx = tid; idx < 8192; idx += 256) ((float*)ol)[idx] = ob[idx];
    __syncthreads();

    const int c = tid & 127, half = tid >> 7;
    float acc[32];
#pragma unroll
    for (int r = 0; r < 32; r++) acc[r] = 0.f;

    for (int k = 0; k < 128; k += 4) {
        float w0 = wp[(k + 0) * 128 + c];
        float w1 = wp[(k + 1) * 128 + c];
        float w2 = wp[(k + 2) * 128 + c];
        float w3 = wp[(k + 3) * 128 + c];
#pragma unroll
        for (int r = 0; r < 32; r++) {
            float4 xv = *(const float4*)&ol[half * 32 + r][k];
            acc[r] += xv.x * w0 + xv.y * w1 + xv.z * w2 + xv.w * w3;
        }
    }

    const float bv = bp[c];
#pragma unroll
    for (int r = 0; r < 32; r++) {
        int rr = half * 32 + r;
        res[rr][(c + rr) & 127] = acc[r] + bv;  // rotate -> conflict-free reads
    }
    __syncthreads();

    // store: lanes = t (contiguous 64*fp32 = 256 B runs per channel)
    const int b_ = tile / 25, n_ = tile % 25;
    const int t_ = tid & 63, cg = tid >> 6;
    const size_t base = (size_t)b_ * 819200 + (size_t)n_ * 64 + t_;
#pragma unroll
    for (int i = 0; i < 32; i++) {
        int c2 = cg + 4 * i;
        out[base + (size_t)(c2 * 4 + grp) * 1600] = res[t_][(c2 + t_) & 127];
    }
}

// ---------------------------------------------------------------------------
// Kernel 4: identity group (x channels [0:128]) -> out channels {0,4,...,508}
// ---------------------------------------------------------------------------
__global__ __launch_bounds__(256) void id_copy(const float* __restrict__ x,
                                               float* __restrict__ out)
{
    const int bn = blockIdx.x;          // 0..199 = b*25+n
    const int b_ = bn / 25, n_ = bn % 25;

    __shared__ float lds[64][130];      // +2 pad
    const int tid = threadIdx.x;
    for (int idx = tid; idx < 8192; idx += 256) {
        int row = idx >> 7, c2 = idx & 127;
        lds[row][c2] = x[(size_t)(bn * 64 + row) * 512 + c2];
    }
    __syncthreads();

    const int t_ = tid & 63, cg = tid >> 6;
    const size_t base = (size_t)b_ * 819200 + (size_t)n_ * 64 + t_;
#pragma unroll
    for (int i = 0; i < 32; i++) {
        int c2 = cg + 4 * i;
        out[base + (size_t)(c2 * 4 + 0) * 1600] = lds[t_][c2];
    }
}

// ---------------------------------------------------------------------------
extern "C" void kernel_launch(void* const* d_in, const int* in_sizes, int n_in,
                              void* d_out, int out_size, void* d_ws, size_t ws_size,
                              hipStream_t stream)
{
    const float* x        = (const float*)d_in[0];
    const float* t_wqkv   = (const float*)d_in[1];
    const float* t_bqkv   = (const float*)d_in[2];
    const float* t_wproj  = (const float*)d_in[3];
    const float* t_bproj  = (const float*)d_in[4];
    const float* s_wqkv   = (const float*)d_in[5];
    const float* s_bqkv   = (const float*)d_in[6];
    const float* s_wproj  = (const float*)d_in[7];
    const float* s_bproj  = (const float*)d_in[8];
    const float* st_wqkv  = (const float*)d_in[9];
    const float* st_bqkv  = (const float*)d_in[10];
    const float* st_wproj = (const float*)d_in[11];
    const float* st_bproj = (const float*)d_in[12];

    float* q  = (float*)d_ws;           // 4 shared fp32 buffers, 26.2 MB total
    float* k  = q + BUF;
    float* v  = q + 2 * BUF;
    float* ob = q + 3 * BUF;
    float* out = (float*)d_out;

    // t branch: x slice [384:512], grp 1
    qkv_proj<<<800, 384, 0, stream>>>(x, t_wqkv, t_bqkv, 0, 384, q, k, v);
    attn_small<0, 64><<<200, 512, 0, stream>>>(q, k, v, ob);
    proj_out<<<200, 256, 0, stream>>>(ob, t_wproj, t_bproj, 1, out);

    // s branch: x slice [256:384], grp 2
    qkv_proj<<<800, 384, 0, stream>>>(x, s_wqkv, s_bqkv, 1, 256, q, k, v);
    attn_small<1, 25><<<512, 256, 0, stream>>>(q, k, v, ob);
    proj_out<<<200, 256, 0, stream>>>(ob, s_wproj, s_bproj, 2, out);

    // st branch: x slice [128:256], grp 3
    qkv_proj<<<800, 384, 0, stream>>>(x, st_wqkv, st_bqkv, 2, 128, q, k, v);
    attn_st<<<448, 256, 0, stream>>>(q, k, v, ob);
    proj_out<<<200, 256, 0, stream>>>(ob, st_wproj, st_bproj, 3, out);

    // identity group, grp 0
    id_copy<<<200, 256, 0, stream>>>(x, out);
}

// Round 4
// 402.364 us; speedup vs baseline: 2.1221x; 2.1221x over previous
//
#include <hip/hip_runtime.h>
#include <hip/hip_bf16.h>

// Problem: b=8, n=25, t=64, C=512, PC=128, heads=8, d=16
// Inputs fp32 (bf16-rounded values), output fp32; harness threshold ~9.75e-2.
#define SCALE 0.25f           // d^-0.5, d=16
#define BUF   1638400ull      // 12800 tokens * 128 ch (one q/k/v/ob buffer)

typedef __attribute__((ext_vector_type(4))) float f4;
typedef __attribute__((ext_vector_type(8))) short s8v;   // 8 bf16 in 4 VGPRs

__device__ __forceinline__ short f2bf(float f) {
    __hip_bfloat16 h = __float2bfloat16(f);
    short s; __builtin_memcpy(&s, &h, 2); return s;
}
__device__ __forceinline__ unsigned pack2(float a, float b) {
    __hip_bfloat16 ha = __float2bfloat16(a), hb = __float2bfloat16(b);
    unsigned short lo, hi;
    __builtin_memcpy(&lo, &ha, 2); __builtin_memcpy(&hi, &hb, 2);
    return (unsigned)lo | ((unsigned)hi << 16);
}

// ---------------------------------------------------------------------------
// Kernel 1: QKV projection for ONE branch (unchanged except br2 V-transpose).
// br=2 V is written TRANSPOSED: vb[(bh*16 + dd)*1600 + seq]  ([bh][d][seq])
// ---------------------------------------------------------------------------
__global__ __launch_bounds__(384) void qkv_proj(
    const float* __restrict__ x, const float* __restrict__ w,
    const float* __restrict__ bias, int br, int off,
    float* __restrict__ qb, float* __restrict__ kb, float* __restrict__ vb)
{
    const int g0 = blockIdx.x * 16;

    __shared__ float xl[16][128];
    const int tid = threadIdx.x;
    for (int idx = tid; idx < 16 * 128; idx += 384) {
        int r = idx >> 7, k = idx & 127;
        xl[r][k] = x[(size_t)(g0 + r) * 512 + off + k];
    }
    __syncthreads();

    const int c = tid;
    float acc[16];
#pragma unroll
    for (int r = 0; r < 16; r++) acc[r] = 0.f;

    for (int k = 0; k < 128; k += 4) {
        float w0 = w[(k + 0) * 384 + c];
        float w1 = w[(k + 1) * 384 + c];
        float w2 = w[(k + 2) * 384 + c];
        float w3 = w[(k + 3) * 384 + c];
#pragma unroll
        for (int r = 0; r < 16; r++) {
            float4 xv = *(const float4*)&xl[r][k];
            acc[r] += xv.x * w0 + xv.y * w1 + xv.z * w2 + xv.w * w3;
        }
    }

    const float bv  = bias[c];
    const int which = c >> 7;          // 0=q 1=k 2=v
    const int rem   = c & 127;
    const int h     = rem >> 4;
    const int dd    = rem & 15;
    float* outbuf = (which == 0) ? qb : (which == 1) ? kb : vb;

#pragma unroll
    for (int r = 0; r < 16; r++) {
        int g = g0 + r;            // token index = (b*25+n)*64 + t
        int batch, seq, N;
        if (br == 0)      { batch = g >> 6; seq = g & 63; N = 64; }
        else if (br == 1) { int b_ = g / 1600, rm = g % 1600;
                            batch = b_ * 64 + (rm & 63); seq = rm >> 6; N = 25; }
        else              { batch = g / 1600; seq = g % 1600; N = 1600; }
        if (br == 2 && which == 2) {
            // transposed: [bh][dd][seq], bh = batch*8 + h
            outbuf[((size_t)batch * 128 + rem) * 1600 + seq] = acc[r] + bv;
        } else {
            outbuf[(((size_t)batch * 8 + h) * N + seq) * 16 + dd] = acc[r] + bv;
        }
    }
}

// ---------------------------------------------------------------------------
// Kernel 2a: scalar attention for t (N=64) and s (N=25). Unchanged.
// ---------------------------------------------------------------------------
template<int BR, int N>
__global__ __launch_bounds__(512) void attn_small(
    const float* __restrict__ qb, const float* __restrict__ kb,
    const float* __restrict__ vb, float* __restrict__ ob)
{
    const int batch = blockIdx.x;
    __shared__ float kl[8 * N * 16];
    __shared__ float vl[8 * N * 16];

    const int tid = threadIdx.x;
    const float* kg = kb + (size_t)batch * 8 * N * 16;
    const float* vg = vb + (size_t)batch * 8 * N * 16;
    for (int idx = tid; idx < 8 * N * 16; idx += blockDim.x) {
        kl[idx] = kg[idx];
        vl[idx] = vg[idx];
    }
    __syncthreads();

    const int h = tid / N, row = tid % N;
    if (h < 8) {
        const float* qrow = qb + (((size_t)batch * 8 + h) * N + row) * 16;
        float q[16];
#pragma unroll
        for (int i = 0; i < 16; i++) q[i] = qrow[i];

        float m = -1e30f, l = 0.f, o[16];
#pragma unroll
        for (int i = 0; i < 16; i++) o[i] = 0.f;

        for (int j = 0; j < N; j++) {
            const float* kj = &kl[(h * N + j) * 16];
            float s = 0.f;
#pragma unroll
            for (int i = 0; i < 16; i++) s += q[i] * kj[i];
            s *= SCALE;
            float mn   = fmaxf(m, s);
            float corr = __expf(m - mn);
            float p    = __expf(s - mn);
            l = l * corr + p;
            const float* vj = &vl[(h * N + j) * 16];
#pragma unroll
            for (int i = 0; i < 16; i++) o[i] = o[i] * corr + p * vj[i];
            m = mn;
        }

        const float inv = 1.f / l;
        int g;
        if (BR == 0) g = batch * 64 + row;
        else { int b_ = batch >> 6, t_ = batch & 63;
               g = b_ * 1600 + row * 64 + t_; }
        float* orow = ob + (size_t)g * 128 + h * 16;
#pragma unroll
        for (int i = 0; i < 16; i++) orow[i] = o[i] * inv;
    }
}

// ---------------------------------------------------------------------------
// Kernel 2b: MFMA flash attention for st (N=1600, 64 bh).
// grid = 64 bh x 25 q-blocks (64 q-rows; 4 waves x 16). No-max softmax.
// S^T = K.Q^T with permuted key rows so exp'd C-frag IS the PV A-frag.
// K LDS [key][16] bf16; V LDS transposed [d][key] bf16 (global already [bh][d][seq]).
// ---------------------------------------------------------------------------
#define CH 160   // keys per LDS chunk (1600 = 10*160; 160 = 5 steps of 32)

__global__ __launch_bounds__(256) void attn_st_mfma(
    const float* __restrict__ qb, const float* __restrict__ kb,
    const float* __restrict__ vtb, float* __restrict__ ob)
{
    __shared__ short kl[CH * 16 + 8];     // [key][d] bf16 + 16B zero pad
    __shared__ short vt[16][CH + 8];      // [d][key] bf16, row pad -> 2-way max

    const int bh  = blockIdx.x / 25;      // batch*8 + head
    const int blk = blockIdx.x % 25;      // 64-q-row block
    const int tid = threadIdx.x;
    const int wave = tid >> 6, lane = tid & 63;
    const int c = lane & 15, g = lane >> 4;
    const int qt0 = blk * 64 + wave * 16; // this wave's 16 q rows

    const float* qg  = qb  + (size_t)bh * 1600 * 16;
    const float* kg  = kb  + (size_t)bh * 1600 * 16;
    const float* vtg = vtb + (size_t)bh * 16 * 1600;

    // Q B-frag: B[n=q=c][k=d=8g+j]; zero for g>=2 (d only 16 wide)
    s8v qf;
    if (g < 2) {
        const float* qr = qg + (size_t)(qt0 + c) * 16 + 8 * g;
#pragma unroll
        for (int j = 0; j < 8; j++) qf[j] = f2bf(qr[j]);
    } else {
#pragma unroll
        for (int j = 0; j < 8; j++) qf[j] = 0;
    }

    f4 oacc = {0.f, 0.f, 0.f, 0.f};
    float lsum = 0.f;

    const int krow_base = 8 * (c >> 2) + (c & 3);   // key perm within 32-key step

    for (int chunk = 0; chunk < 10; chunk++) {
        const int kb0 = chunk * CH;
        __syncthreads();
        // stage K chunk: [key][d] bf16, pair-packed u32 writes (conflict-free)
        for (int i = tid; i < CH * 8; i += 256) {           // 1280 pairs
            int key = i >> 3, dp = i & 7;
            const float* src = kg + (size_t)(kb0 + key) * 16 + dp * 2;
            ((unsigned*)kl)[key * 8 + dp] = pack2(src[0], src[1]);
        }
        // stage V^T chunk: vt[d][key], pair-packed along key (conflict-free)
        for (int i = tid; i < 16 * (CH / 2); i += 256) {    // 1280 pairs
            int d = i / (CH / 2), kp = i % (CH / 2);
            const float* src = vtg + (size_t)d * 1600 + kb0 + kp * 2;
            *(unsigned*)&vt[d][kp * 2] = pack2(src[0], src[1]);
        }
        if (tid < 8) kl[CH * 16 + tid] = 0;                 // zero pad for g>=2 reads
        __syncthreads();

        for (int s = 0; s < 5; s++) {                       // 32 keys per step
            const int kr0 = s * 32 + krow_base;
            // K A-frags (tau=0,1): A[m][k=d]; lanes g>=2 read the zero pad
            s8v kf0 = *(const s8v*)&kl[g < 2 ? (kr0 * 16 + 8 * g)       : CH * 16];
            s8v kf1 = *(const s8v*)&kl[g < 2 ? ((kr0 + 4) * 16 + 8 * g) : CH * 16];
            // V B-frag: B[n=dout=c][k=key=8g+j]
            s8v vf  = *(const s8v*)&vt[c][s * 32 + 8 * g];

            f4 sa = {0.f, 0.f, 0.f, 0.f}, sb = {0.f, 0.f, 0.f, 0.f};
            sa = __builtin_amdgcn_mfma_f32_16x16x32_bf16(kf0, qf, sa, 0, 0, 0);
            sb = __builtin_amdgcn_mfma_f32_16x16x32_bf16(kf1, qf, sb, 0, 0, 0);

            // lane holds S^T[key=s*32+8g+4tau+r][q=c] -> exp -> PV A-frag order j=4tau+r
            float p[8];
#pragma unroll
            for (int r = 0; r < 4; r++) {
                p[r]     = __expf(sa[r] * SCALE);
                p[r + 4] = __expf(sb[r] * SCALE);
            }
            s8v pf;
#pragma unroll
            for (int j = 0; j < 8; j++) { lsum += p[j]; pf[j] = f2bf(p[j]); }

            oacc = __builtin_amdgcn_mfma_f32_16x16x32_bf16(pf, vf, oacc, 0, 0, 0);
        }
    }

    // l[q=c] = sum over lanes c, c+16, c+32, c+48
    lsum += __shfl_xor(lsum, 16);
    lsum += __shfl_xor(lsum, 32);

    // O C-layout: row q' = qt0 + 4g + r, col dout = c; fetch l for q' via shfl
    const int batch = bh >> 3, h = bh & 7;
#pragma unroll
    for (int r = 0; r < 4; r++) {
        float li = __shfl(lsum, 4 * g + r);     // lane 4g+r holds l for q'=4g+r
        int qrow = qt0 + 4 * g + r;
        ob[((size_t)batch * 1600 + qrow) * 128 + h * 16 + c] = oacc[r] / li;
    }
}

// ---------------------------------------------------------------------------
// Kernel 3: output projection + concat/transpose/channel-shuffle. Unchanged.
// ---------------------------------------------------------------------------
__global__ __launch_bounds__(256) void proj_out(
    const float* __restrict__ ob_, const float* __restrict__ wp,
    const float* __restrict__ bp, int grp, float* __restrict__ out)
{
    const int tile = blockIdx.x;
    const float* ob = ob_ + (size_t)tile * 64 * 128;

    __shared__ float ol[64][128];
    __shared__ float res[64][128];

    const int tid = threadIdx.x;
    for (int idx = tid; idx < 8192; idx += 256) ((float*)ol)[idx] = ob[idx];
    __syncthreads();

    const int c = tid & 127, half = tid >> 7;
    float acc[32];
#pragma unroll
    for (int r = 0; r < 32; r++) acc[r] = 0.f;

    for (int k = 0; k < 128; k += 4) {
        float w0 = wp[(k + 0) * 128 + c];
        float w1 = wp[(k + 1) * 128 + c];
        float w2 = wp[(k + 2) * 128 + c];
        float w3 = wp[(k + 3) * 128 + c];
#pragma unroll
        for (int r = 0; r < 32; r++) {
            float4 xv = *(const float4*)&ol[half * 32 + r][k];
            acc[r] += xv.x * w0 + xv.y * w1 + xv.z * w2 + xv.w * w3;
        }
    }

    const float bv = bp[c];
#pragma unroll
    for (int r = 0; r < 32; r++) {
        int rr = half * 32 + r;
        res[rr][(c + rr) & 127] = acc[r] + bv;
    }
    __syncthreads();

    const int b_ = tile / 25, n_ = tile % 25;
    const int t_ = tid & 63, cg = tid >> 6;
    const size_t base = (size_t)b_ * 819200 + (size_t)n_ * 64 + t_;
#pragma unroll
    for (int i = 0; i < 32; i++) {
        int c2 = cg + 4 * i;
        out[base + (size_t)(c2 * 4 + grp) * 1600] = res[t_][(c2 + t_) & 127];
    }
}

// ---------------------------------------------------------------------------
// Kernel 4: identity group. Unchanged.
// ---------------------------------------------------------------------------
__global__ __launch_bounds__(256) void id_copy(const float* __restrict__ x,
                                               float* __restrict__ out)
{
    const int bn = blockIdx.x;
    const int b_ = bn / 25, n_ = bn % 25;

    __shared__ float lds[64][130];
    const int tid = threadIdx.x;
    for (int idx = tid; idx < 8192; idx += 256) {
        int row = idx >> 7, c2 = idx & 127;
        lds[row][c2] = x[(size_t)(bn * 64 + row) * 512 + c2];
    }
    __syncthreads();

    const int t_ = tid & 63, cg = tid >> 6;
    const size_t base = (size_t)b_ * 819200 + (size_t)n_ * 64 + t_;
#pragma unroll
    for (int i = 0; i < 32; i++) {
        int c2 = cg + 4 * i;
        out[base + (size_t)(c2 * 4 + 0) * 1600] = lds[t_][c2];
    }
}

// ---------------------------------------------------------------------------
extern "C" void kernel_launch(void* const* d_in, const int* in_sizes, int n_in,
                              void* d_out, int out_size, void* d_ws, size_t ws_size,
                              hipStream_t stream)
{
    const float* x        = (const float*)d_in[0];
    const float* t_wqkv   = (const float*)d_in[1];
    const float* t_bqkv   = (const float*)d_in[2];
    const float* t_wproj  = (const float*)d_in[3];
    const float* t_bproj  = (const float*)d_in[4];
    const float* s_wqkv   = (const float*)d_in[5];
    const float* s_bqkv   = (const float*)d_in[6];
    const float* s_wproj  = (const float*)d_in[7];
    const float* s_bproj  = (const float*)d_in[8];
    const float* st_wqkv  = (const float*)d_in[9];
    const float* st_bqkv  = (const float*)d_in[10];
    const float* st_wproj = (const float*)d_in[11];
    const float* st_bproj = (const float*)d_in[12];

    float* q  = (float*)d_ws;
    float* k  = q + BUF;
    float* v  = q + 2 * BUF;
    float* ob = q + 3 * BUF;
    float* out = (float*)d_out;

    // t branch: x slice [384:512], grp 1
    qkv_proj<<<800, 384, 0, stream>>>(x, t_wqkv, t_bqkv, 0, 384, q, k, v);
    attn_small<0, 64><<<200, 512, 0, stream>>>(q, k, v, ob);
    proj_out<<<200, 256, 0, stream>>>(ob, t_wproj, t_bproj, 1, out);

    // s branch: x slice [256:384], grp 2
    qkv_proj<<<800, 384, 0, stream>>>(x, s_wqkv, s_bqkv, 1, 256, q, k, v);
    attn_small<1, 25><<<512, 256, 0, stream>>>(q, k, v, ob);
    proj_out<<<200, 256, 0, stream>>>(ob, s_wproj, s_bproj, 2, out);

    // st branch: x slice [128:256], grp 3 (V written transposed [bh][d][seq])
    qkv_proj<<<800, 384, 0, stream>>>(x, st_wqkv, st_bqkv, 2, 128, q, k, v);
    attn_st_mfma<<<1600, 256, 0, stream>>>(q, k, v, ob);
    proj_out<<<200, 256, 0, stream>>>(ob, st_wproj, st_bproj, 3, out);

    // identity group, grp 0
    id_copy<<<200, 256, 0, stream>>>(x, out);
}

// Round 5
// 261.973 us; speedup vs baseline: 3.2594x; 1.5359x over previous
//
#include <hip/hip_runtime.h>
#include <hip/hip_bf16.h>

// Problem: b=8, n=25, t=64, C=512, PC=128, heads=8, d=16
// Inputs fp32 (bf16-rounded values), output fp32; harness threshold ~9.75e-2.
#define SCALE 0.25f           // d^-0.5, d=16
#define BUF   1638400ull      // 12800 tokens * 128 ch (one q/k/v/ob buffer)

typedef __attribute__((ext_vector_type(4))) float f4;
typedef __attribute__((ext_vector_type(8))) short s8v;   // 8 bf16 in 4 VGPRs

__device__ __forceinline__ short f2bf(float f) {
    __hip_bfloat16 h = __float2bfloat16(f);
    short s; __builtin_memcpy(&s, &h, 2); return s;
}
__device__ __forceinline__ unsigned pack2(float a, float b) {
    __hip_bfloat16 ha = __float2bfloat16(a), hb = __float2bfloat16(b);
    unsigned short lo, hi;
    __builtin_memcpy(&lo, &ha, 2); __builtin_memcpy(&hi, &hb, 2);
    return (unsigned)lo | ((unsigned)hi << 16);
}

// ---------------------------------------------------------------------------
// Kernel 0: prep — convert x to bf16 (row-major) and swizzle all 6 weight
// matrices into B-fragment order: wsw[((nt*4+ks)*64+lane)*8+j] =
//   W[ks*32 + 8*(lane>>4) + j][nt*16 + (lane&15)]
// Concat order: wq_t(49152) wq_s wq_st wp_t(16384) wp_s wp_st  (196608 total)
// ---------------------------------------------------------------------------
__global__ __launch_bounds__(256) void prep(
    const float* __restrict__ x,
    const float* __restrict__ wq0, const float* __restrict__ wq1,
    const float* __restrict__ wq2,
    const float* __restrict__ wp0, const float* __restrict__ wp1,
    const float* __restrict__ wp2,
    short* __restrict__ xbf, short* __restrict__ wsw)
{
    const int blk = blockIdx.x, tid = threadIdx.x;
    if (blk < 3200) {                       // x: 6,553,600 elems = 3200*2048
        const int base = blk * 2048 + tid * 8;
        float4 a = *(const float4*)(x + base);
        float4 b = *(const float4*)(x + base + 4);
        s8v o;
        o[0] = f2bf(a.x); o[1] = f2bf(a.y); o[2] = f2bf(a.z); o[3] = f2bf(a.w);
        o[4] = f2bf(b.x); o[5] = f2bf(b.y); o[6] = f2bf(b.z); o[7] = f2bf(b.w);
        *(s8v*)(xbf + base) = o;
    } else {                                // weights: 196608 = 96*2048
        const int idx0 = (blk - 3200) * 2048 + tid * 8;   // j = 0..7 within
        const float* W; int Ncols, loc = idx0;
        if      (idx0 < 49152)  { W = wq0; Ncols = 384; }
        else if (idx0 < 98304)  { W = wq1; Ncols = 384; loc -= 49152; }
        else if (idx0 < 147456) { W = wq2; Ncols = 384; loc -= 98304; }
        else if (idx0 < 163840) { W = wp0; Ncols = 128; loc -= 147456; }
        else if (idx0 < 180224) { W = wp1; Ncols = 128; loc -= 163840; }
        else                    { W = wp2; Ncols = 128; loc -= 180224; }
        const int lane = (loc >> 3) & 63, ks = (loc >> 9) & 3, nt = loc >> 11;
        const int col = nt * 16 + (lane & 15);
        const int k0  = ks * 32 + 8 * (lane >> 4);
        s8v o;
#pragma unroll
        for (int j = 0; j < 8; j++) o[j] = f2bf(W[(k0 + j) * Ncols + col]);
        *(s8v*)(wsw + idx0) = o;
    }
}

// ---------------------------------------------------------------------------
// Kernel 1: MFMA QKV projection for ONE branch.
// grid = 800 blocks (16 tokens), block = 256 (4 waves x 6 ntiles of 16 cols).
// A-frags direct from global bf16 (no LDS); B-frags from pre-swizzled wsw.
// Output layouts identical to previous scalar kernel (incl. br2 V transpose).
// ---------------------------------------------------------------------------
__global__ __launch_bounds__(256) void qkv_mfma(
    const short* __restrict__ xbf, const short* __restrict__ wsw,
    const float* __restrict__ bias, int br, int off,
    float* __restrict__ qb, float* __restrict__ kb, float* __restrict__ vb)
{
    const int tok0 = blockIdx.x * 16;
    const int wave = threadIdx.x >> 6, lane = threadIdx.x & 63;
    const int c = lane & 15, gq = lane >> 4;

    // A-frags: A[m=c][k=ks*32+8gq+j] from xbf row tok0+c
    const short* xrow = xbf + (size_t)(tok0 + c) * 512 + off + 8 * gq;
    s8v af[4];
#pragma unroll
    for (int ks = 0; ks < 4; ks++) af[ks] = *(const s8v*)(xrow + ks * 32);

    // branch-uniform scalars
    const int batch0 = tok0 >> 6;                 // br0
    const int b_     = tok0 / 1600;               // br1/br2
    const int rm0    = tok0 - b_ * 1600;
    const int seq1   = rm0 >> 6;                  // br1 seq (const in tile)

    for (int nti = 0; nti < 6; nti++) {
        const int nt = wave * 6 + nti;            // 0..23
        const short* bp = wsw + ((size_t)(nt * 4) * 64 + lane) * 8;
        f4 acc = {0.f, 0.f, 0.f, 0.f};
#pragma unroll
        for (int ks = 0; ks < 4; ks++) {
            s8v bf = *(const s8v*)(bp + ks * 512);
            acc = __builtin_amdgcn_mfma_f32_16x16x32_bf16(af[ks], bf, acc, 0, 0, 0);
        }
        const int col = nt * 16 + c;
        const float bv = bias[col];
        const int which = nt >> 3, h = nt & 7;    // rem = h*16 + c, dd = c
        float* ob = (which == 0) ? qb : (which == 1) ? kb : vb;

        if (br == 0) {
            // ((batch*8+h)*64 + seq)*16 + c, seq = (tok0&63)+4gq+r
            float* p = ob + (((size_t)batch0 * 8 + h) * 64 + (tok0 & 63) + 4 * gq) * 16 + c;
#pragma unroll
            for (int r = 0; r < 4; r++) p[r * 16] = acc[r] + bv;
        } else if (br == 1) {
            // batch = b_*64 + (rm&63), seq = rm>>6; rm = rm0+4gq+r
            const int bt0 = b_ * 64 + (rm0 & 63) + 4 * gq;
            float* p = ob + (((size_t)bt0 * 8 + h) * 25 + seq1) * 16 + c;
#pragma unroll
            for (int r = 0; r < 4; r++) p[(size_t)r * 3200] = acc[r] + bv;  // 8*25*16
        } else {
            const int seq0 = rm0 + 4 * gq;
            if (which == 2) {
                // V transposed: vb[(b_*128 + h*16 + c)*1600 + seq], r contiguous
                float4 st = {acc[0] + bv, acc[1] + bv, acc[2] + bv, acc[3] + bv};
                *(float4*)(ob + ((size_t)b_ * 128 + h * 16 + c) * 1600 + seq0) = st;
            } else {
                float* p = ob + (((size_t)b_ * 8 + h) * 1600 + seq0) * 16 + c;
#pragma unroll
                for (int r = 0; r < 4; r++) p[r * 16] = acc[r] + bv;
            }
        }
    }
}

// ---------------------------------------------------------------------------
// Kernel 2a: scalar attention for t (N=64) and s (N=25). Unchanged.
// ---------------------------------------------------------------------------
template<int BR, int N>
__global__ __launch_bounds__(512) void attn_small(
    const float* __restrict__ qb, const float* __restrict__ kb,
    const float* __restrict__ vb, float* __restrict__ ob)
{
    const int batch = blockIdx.x;
    __shared__ float kl[8 * N * 16];
    __shared__ float vl[8 * N * 16];

    const int tid = threadIdx.x;
    const float* kg = kb + (size_t)batch * 8 * N * 16;
    const float* vg = vb + (size_t)batch * 8 * N * 16;
    for (int idx = tid; idx < 8 * N * 16; idx += blockDim.x) {
        kl[idx] = kg[idx];
        vl[idx] = vg[idx];
    }
    __syncthreads();

    const int h = tid / N, row = tid % N;
    if (h < 8) {
        const float* qrow = qb + (((size_t)batch * 8 + h) * N + row) * 16;
        float q[16];
#pragma unroll
        for (int i = 0; i < 16; i++) q[i] = qrow[i];

        float m = -1e30f, l = 0.f, o[16];
#pragma unroll
        for (int i = 0; i < 16; i++) o[i] = 0.f;

        for (int j = 0; j < N; j++) {
            const float* kj = &kl[(h * N + j) * 16];
            float s = 0.f;
#pragma unroll
            for (int i = 0; i < 16; i++) s += q[i] * kj[i];
            s *= SCALE;
            float mn   = fmaxf(m, s);
            float corr = __expf(m - mn);
            float p    = __expf(s - mn);
            l = l * corr + p;
            const float* vj = &vl[(h * N + j) * 16];
#pragma unroll
            for (int i = 0; i < 16; i++) o[i] = o[i] * corr + p * vj[i];
            m = mn;
        }

        const float inv = 1.f / l;
        int g;
        if (BR == 0) g = batch * 64 + row;
        else { int b2 = batch >> 6, t_ = batch & 63;
               g = b2 * 1600 + row * 64 + t_; }
        float* orow = ob + (size_t)g * 128 + h * 16;
#pragma unroll
        for (int i = 0; i < 16; i++) orow[i] = o[i] * inv;
    }
}

// ---------------------------------------------------------------------------
// Kernel 2b: MFMA flash attention for st (N=1600, 64 bh). Unchanged.
// ---------------------------------------------------------------------------
#define CH 160

__global__ __launch_bounds__(256) void attn_st_mfma(
    const float* __restrict__ qb, const float* __restrict__ kb,
    const float* __restrict__ vtb, float* __restrict__ ob)
{
    __shared__ short kl[CH * 16 + 8];
    __shared__ short vt[16][CH + 8];

    const int bh  = blockIdx.x / 25;
    const int blk = blockIdx.x % 25;
    const int tid = threadIdx.x;
    const int wave = tid >> 6, lane = tid & 63;
    const int c = lane & 15, g = lane >> 4;
    const int qt0 = blk * 64 + wave * 16;

    const float* qg  = qb  + (size_t)bh * 1600 * 16;
    const float* kg  = kb  + (size_t)bh * 1600 * 16;
    const float* vtg = vtb + (size_t)bh * 16 * 1600;

    s8v qf;
    if (g < 2) {
        const float* qr = qg + (size_t)(qt0 + c) * 16 + 8 * g;
#pragma unroll
        for (int j = 0; j < 8; j++) qf[j] = f2bf(qr[j]);
    } else {
#pragma unroll
        for (int j = 0; j < 8; j++) qf[j] = 0;
    }

    f4 oacc = {0.f, 0.f, 0.f, 0.f};
    float lsum = 0.f;

    const int krow_base = 8 * (c >> 2) + (c & 3);

    for (int chunk = 0; chunk < 10; chunk++) {
        const int kb0 = chunk * CH;
        __syncthreads();
        for (int i = tid; i < CH * 8; i += 256) {
            int key = i >> 3, dp = i & 7;
            const float* src = kg + (size_t)(kb0 + key) * 16 + dp * 2;
            ((unsigned*)kl)[key * 8 + dp] = pack2(src[0], src[1]);
        }
        for (int i = tid; i < 16 * (CH / 2); i += 256) {
            int d = i / (CH / 2), kp = i % (CH / 2);
            const float* src = vtg + (size_t)d * 1600 + kb0 + kp * 2;
            *(unsigned*)&vt[d][kp * 2] = pack2(src[0], src[1]);
        }
        if (tid < 8) kl[CH * 16 + tid] = 0;
        __syncthreads();

        for (int s = 0; s < 5; s++) {
            const int kr0 = s * 32 + krow_base;
            s8v kf0 = *(const s8v*)&kl[g < 2 ? (kr0 * 16 + 8 * g)       : CH * 16];
            s8v kf1 = *(const s8v*)&kl[g < 2 ? ((kr0 + 4) * 16 + 8 * g) : CH * 16];
            s8v vf  = *(const s8v*)&vt[c][s * 32 + 8 * g];

            f4 sa = {0.f, 0.f, 0.f, 0.f}, sb = {0.f, 0.f, 0.f, 0.f};
            sa = __builtin_amdgcn_mfma_f32_16x16x32_bf16(kf0, qf, sa, 0, 0, 0);
            sb = __builtin_amdgcn_mfma_f32_16x16x32_bf16(kf1, qf, sb, 0, 0, 0);

            float p[8];
#pragma unroll
            for (int r = 0; r < 4; r++) {
                p[r]     = __expf(sa[r] * SCALE);
                p[r + 4] = __expf(sb[r] * SCALE);
            }
            s8v pf;
#pragma unroll
            for (int j = 0; j < 8; j++) { lsum += p[j]; pf[j] = f2bf(p[j]); }

            oacc = __builtin_amdgcn_mfma_f32_16x16x32_bf16(pf, vf, oacc, 0, 0, 0);
        }
    }

    lsum += __shfl_xor(lsum, 16);
    lsum += __shfl_xor(lsum, 32);

    const int batch = bh >> 3, h = bh & 7;
#pragma unroll
    for (int r = 0; r < 4; r++) {
        float li = __shfl(lsum, 4 * g + r);
        int qrow = qt0 + 4 * g + r;
        ob[((size_t)batch * 1600 + qrow) * 128 + h * 16 + c] = oacc[r] / li;
    }
}

// ---------------------------------------------------------------------------
// Kernel 3: MFMA output projection + bias + fused channel-shuffle store.
// grid = 800 blocks (16 tokens), block = 256 (4 waves x 2 ntiles).
// out[b, c2*4+grp, n, t]; r-index = consecutive t -> aligned float4 stores.
// ---------------------------------------------------------------------------
__global__ __launch_bounds__(256) void proj_mfma(
    const float* __restrict__ ob_, const short* __restrict__ wsw,
    const float* __restrict__ bp, int grp, float* __restrict__ out)
{
    const int blk = blockIdx.x;
    const int tok0 = blk * 16;
    const int wave = threadIdx.x >> 6, lane = threadIdx.x & 63;
    const int c = lane & 15, gq = lane >> 4;

    // A-frags: ob row tok0+c (fp32, coalesced 32 B/lane per kstep) -> bf16
    const float* arow = ob_ + (size_t)(tok0 + c) * 128 + 8 * gq;
    s8v af[4];
#pragma unroll
    for (int ks = 0; ks < 4; ks++) {
        float4 a = *(const float4*)(arow + ks * 32);
        float4 b = *(const float4*)(arow + ks * 32 + 4);
        af[ks][0] = f2bf(a.x); af[ks][1] = f2bf(a.y);
        af[ks][2] = f2bf(a.z); af[ks][3] = f2bf(a.w);
        af[ks][4] = f2bf(b.x); af[ks][5] = f2bf(b.y);
        af[ks][6] = f2bf(b.z); af[ks][7] = f2bf(b.w);
    }

    const int bn = blk >> 2;                 // token>>6 = (b*25+n)
    const int b_ = bn / 25, n_ = bn % 25;
    const int t0 = (blk & 3) * 16 + 4 * gq;  // 4 consecutive t per lane

    for (int nti = 0; nti < 2; nti++) {
        const int nt = wave * 2 + nti;       // 0..7
        const short* bpw = wsw + ((size_t)(nt * 4) * 64 + lane) * 8;
        f4 acc = {0.f, 0.f, 0.f, 0.f};
#pragma unroll
        for (int ks = 0; ks < 4; ks++) {
            s8v bf = *(const s8v*)(bpw + ks * 512);
            acc = __builtin_amdgcn_mfma_f32_16x16x32_bf16(af[ks], bf, acc, 0, 0, 0);
        }
        const int c2 = nt * 16 + c;
        const float bv = bp[c2];
        float4 st = {acc[0] + bv, acc[1] + bv, acc[2] + bv, acc[3] + bv};
        *(float4*)(out + (size_t)b_ * 819200 + (size_t)(c2 * 4 + grp) * 1600
                       + n_ * 64 + t0) = st;
    }
}

// ---------------------------------------------------------------------------
// Kernel 4: identity group. Unchanged.
// ---------------------------------------------------------------------------
__global__ __launch_bounds__(256) void id_copy(const float* __restrict__ x,
                                               float* __restrict__ out)
{
    const int bn = blockIdx.x;
    const int b_ = bn / 25, n_ = bn % 25;

    __shared__ float lds[64][130];
    const int tid = threadIdx.x;
    for (int idx = tid; idx < 8192; idx += 256) {
        int row = idx >> 7, c2 = idx & 127;
        lds[row][c2] = x[(size_t)(bn * 64 + row) * 512 + c2];
    }
    __syncthreads();

    const int t_ = tid & 63, cg = tid >> 6;
    const size_t base = (size_t)b_ * 819200 + (size_t)n_ * 64 + t_;
#pragma unroll
    for (int i = 0; i < 32; i++) {
        int c2 = cg + 4 * i;
        out[base + (size_t)(c2 * 4 + 0) * 1600] = lds[t_][c2];
    }
}

// ---------------------------------------------------------------------------
extern "C" void kernel_launch(void* const* d_in, const int* in_sizes, int n_in,
                              void* d_out, int out_size, void* d_ws, size_t ws_size,
                              hipStream_t stream)
{
    const float* x        = (const float*)d_in[0];
    const float* t_wqkv   = (const float*)d_in[1];
    const float* t_bqkv   = (const float*)d_in[2];
    const float* t_wproj  = (const float*)d_in[3];
    const float* t_bproj  = (const float*)d_in[4];
    const float* s_wqkv   = (const float*)d_in[5];
    const float* s_bqkv   = (const float*)d_in[6];
    const float* s_wproj  = (const float*)d_in[7];
    const float* s_bproj  = (const float*)d_in[8];
    const float* st_wqkv  = (const float*)d_in[9];
    const float* st_bqkv  = (const float*)d_in[10];
    const float* st_wproj = (const float*)d_in[11];
    const float* st_bproj = (const float*)d_in[12];

    float* q   = (float*)d_ws;                  // 4 x 6.55 MB fp32
    float* k   = q + BUF;
    float* v   = q + 2 * BUF;
    float* ob  = q + 3 * BUF;
    short* xbf = (short*)(q + 4 * BUF);         // 13.1 MB bf16
    short* wsw = xbf + 6553600ull;              // 393 KB swizzled weights
    float* out = (float*)d_out;

    prep<<<3296, 256, 0, stream>>>(x, t_wqkv, s_wqkv, st_wqkv,
                                   t_wproj, s_wproj, st_wproj, xbf, wsw);

    // t branch: x slice [384:512], grp 1
    qkv_mfma<<<800, 256, 0, stream>>>(xbf, wsw + 0 * 49152, t_bqkv, 0, 384, q, k, v);
    attn_small<0, 64><<<200, 512, 0, stream>>>(q, k, v, ob);
    proj_mfma<<<800, 256, 0, stream>>>(ob, wsw + 147456 + 0 * 16384, t_bproj, 1, out);

    // s branch: x slice [256:384], grp 2
    qkv_mfma<<<800, 256, 0, stream>>>(xbf, wsw + 1 * 49152, s_bqkv, 1, 256, q, k, v);
    attn_small<1, 25><<<512, 256, 0, stream>>>(q, k, v, ob);
    proj_mfma<<<800, 256, 0, stream>>>(ob, wsw + 147456 + 1 * 16384, s_bproj, 2, out);

    // st branch: x slice [128:256], grp 3 (V written transposed [bh][d][seq])
    qkv_mfma<<<800, 256, 0, stream>>>(xbf, wsw + 2 * 49152, st_bqkv, 2, 128, q, k, v);
    attn_st_mfma<<<1600, 256, 0, stream>>>(q, k, v, ob);
    proj_mfma<<<800, 256, 0, stream>>>(ob, wsw + 147456 + 2 * 16384, st_bproj, 3, out);

    // identity group, grp 0
    id_copy<<<200, 256, 0, stream>>>(x, out);
}

// Round 6
// 189.139 us; speedup vs baseline: 4.5145x; 1.3851x over previous
//
#include <hip/hip_runtime.h>
#include <hip/hip_bf16.h>

// Problem: b=8, n=25, t=64, C=512, PC=128, heads=8, d=16
// Inputs fp32 (bf16-exact values), output fp32; harness threshold ~9.75e-2.
#define BUF   1638400ull      // elements of one q/k/v/ob buffer (12800*128)
#define QSC   0.36067376f     // 0.25 * log2(e): folded into Q; softmax exp -> exp2

typedef __attribute__((ext_vector_type(4))) float f4;
typedef __attribute__((ext_vector_type(8))) short s8v;
typedef __attribute__((ext_vector_type(4))) unsigned u4v;

#if __has_builtin(__builtin_amdgcn_exp2f)
#define EXP2(x) __builtin_amdgcn_exp2f(x)
#else
#define EXP2(x) exp2f(x)
#endif

__device__ __forceinline__ short f2bf(float f) {          // RNE (epilogues)
    __hip_bfloat16 h = __float2bfloat16(f);
    short s; __builtin_memcpy(&s, &h, 2); return s;
}
__device__ __forceinline__ unsigned pack2(float a, float b) {  // RNE pair
    return (unsigned)(unsigned short)f2bf(a) | ((unsigned)(unsigned short)f2bf(b) << 16);
}
__device__ __forceinline__ float bf2f(short s) {
    return __uint_as_float((unsigned)(unsigned short)s << 16);
}
__device__ __forceinline__ unsigned tpack(float hi, float lo) { // trunc pair, 1 instr
    return __builtin_amdgcn_perm(__float_as_uint(hi), __float_as_uint(lo), 0x07060302u);
}

// ---------------------------------------------------------------------------
// Kernel 0: prep — x -> bf16 row-major; 6 weight mats -> bf16 B-frag order:
// wsw[((nt*4+ks)*64+lane)*8+j] = W[ks*32+8*(lane>>4)+j][nt*16+(lane&15)]
// ---------------------------------------------------------------------------
__global__ __launch_bounds__(256) void prep(
    const float* __restrict__ x,
    const float* __restrict__ wq0, const float* __restrict__ wq1,
    const float* __restrict__ wq2,
    const float* __restrict__ wp0, const float* __restrict__ wp1,
    const float* __restrict__ wp2,
    short* __restrict__ xbf, short* __restrict__ wsw)
{
    const int blk = blockIdx.x, tid = threadIdx.x;
    if (blk < 3200) {
        const int base = blk * 2048 + tid * 8;
        float4 a = *(const float4*)(x + base);
        float4 b = *(const float4*)(x + base + 4);
        s8v o;
        o[0]=f2bf(a.x); o[1]=f2bf(a.y); o[2]=f2bf(a.z); o[3]=f2bf(a.w);
        o[4]=f2bf(b.x); o[5]=f2bf(b.y); o[6]=f2bf(b.z); o[7]=f2bf(b.w);
        *(s8v*)(xbf + base) = o;
    } else {
        const int idx0 = (blk - 3200) * 2048 + tid * 8;
        const float* W; int Ncols, loc = idx0;
        if      (idx0 < 49152)  { W = wq0; Ncols = 384; }
        else if (idx0 < 98304)  { W = wq1; Ncols = 384; loc -= 49152; }
        else if (idx0 < 147456) { W = wq2; Ncols = 384; loc -= 98304; }
        else if (idx0 < 163840) { W = wp0; Ncols = 128; loc -= 147456; }
        else if (idx0 < 180224) { W = wp1; Ncols = 128; loc -= 163840; }
        else                    { W = wp2; Ncols = 128; loc -= 180224; }
        const int lane = (loc >> 3) & 63, ks = (loc >> 9) & 3, nt = loc >> 11;
        const int col = nt * 16 + (lane & 15);
        const int k0  = ks * 32 + 8 * (lane >> 4);
        s8v o;
#pragma unroll
        for (int j = 0; j < 8; j++) o[j] = f2bf(W[(k0 + j) * Ncols + col]);
        *(s8v*)(wsw + idx0) = o;
    }
}

// ---------------------------------------------------------------------------
// Kernel 1: fused QKV for all branches -> bf16, V transposed for ALL branches.
// grid 2400 (800/branch, 16 tokens), block 256 (4 waves x 6 ntiles).
// q/k: [bh][seq][16]; v: [bh][16][seq].  bh: t=(b25n)*8+h, s=(b64t)*8+h, st=b*8+h
// ---------------------------------------------------------------------------
__global__ __launch_bounds__(256) void qkv_all(
    const short* __restrict__ xbf, const short* __restrict__ wsw,
    const float* __restrict__ bq0, const float* __restrict__ bq1,
    const float* __restrict__ bq2,
    short* __restrict__ q0, short* __restrict__ k0, short* __restrict__ vt0,
    short* __restrict__ q1, short* __restrict__ k1, short* __restrict__ vt1,
    short* __restrict__ q2, short* __restrict__ k2, short* __restrict__ vt2)
{
    const int br = blockIdx.x / 800, tile = blockIdx.x % 800;
    const int tok0 = tile * 16;
    const int wave = threadIdx.x >> 6, lane = threadIdx.x & 63;
    const int c = lane & 15, gq = lane >> 4;
    const int off = 384 - 128 * br;
    const short* wswb = wsw + br * 49152;
    const float* bias = (br == 0) ? bq0 : (br == 1) ? bq1 : bq2;

    const short* xrow = xbf + (size_t)(tok0 + c) * 512 + off + 8 * gq;
    s8v af[4];
#pragma unroll
    for (int ks = 0; ks < 4; ks++) af[ks] = *(const s8v*)(xrow + ks * 32);

    const int batch0 = tok0 >> 6;
    const int b_  = tok0 / 1600;
    const int rm0 = tok0 - b_ * 1600;
    const int seq1 = rm0 >> 6;

    for (int nti = 0; nti < 6; nti++) {
        const int nt = wave * 6 + nti;
        const short* bp = wswb + ((size_t)(nt * 4) * 64 + lane) * 8;
        f4 acc = {0.f, 0.f, 0.f, 0.f};
#pragma unroll
        for (int ks = 0; ks < 4; ks++) {
            s8v bf = *(const s8v*)(bp + ks * 512);
            acc = __builtin_amdgcn_mfma_f32_16x16x32_bf16(af[ks], bf, acc, 0, 0, 0);
        }
        const float bv = bias[nt * 16 + c];
        const float v0 = acc[0]+bv, v1 = acc[1]+bv, v2 = acc[2]+bv, v3 = acc[3]+bv;
        const int which = nt >> 3, h = nt & 7;

        if (br == 0) {
            const int seq0 = (tok0 & 63) + 4 * gq;
            if (which == 2) {
                unsigned* p = (unsigned*)(vt0 + ((size_t)(batch0*8+h)*16 + c)*64 + seq0);
                p[0] = pack2(v0, v1); p[1] = pack2(v2, v3);
            } else {
                short* p = (which ? k0 : q0) + (((size_t)(batch0*8+h)*64 + seq0)*16 + c);
                p[0]=f2bf(v0); p[16]=f2bf(v1); p[32]=f2bf(v2); p[48]=f2bf(v3);
            }
        } else if (br == 1) {
            const int bt0 = b_ * 64 + (rm0 & 63) + 4 * gq;   // r stride = 8*16*25 = 3200
            if (which == 2) {
                short* p = vt1 + ((size_t)(bt0*8+h)*16 + c)*25 + seq1;
                p[0]=f2bf(v0); p[3200]=f2bf(v1); p[6400]=f2bf(v2); p[9600]=f2bf(v3);
            } else {
                short* p = (which ? k1 : q1) + (((size_t)bt0*8+h)*25 + seq1)*16 + c;
                p[0]=f2bf(v0); p[3200]=f2bf(v1); p[6400]=f2bf(v2); p[9600]=f2bf(v3);
            }
        } else {
            const int seq0 = rm0 + 4 * gq;
            if (which == 2) {
                unsigned* p = (unsigned*)(vt2 + ((size_t)b_*128 + h*16 + c)*1600 + seq0);
                p[0] = pack2(v0, v1); p[1] = pack2(v2, v3);
            } else {
                short* p = (which ? k2 : q2) + (((size_t)b_*8+h)*1600 + seq0)*16 + c;
                p[0]=f2bf(v0); p[16]=f2bf(v1); p[32]=f2bf(v2); p[48]=f2bf(v3);
            }
        }
    }
}

// ---------------------------------------------------------------------------
// Generic MFMA attention core (no-max softmax; S^T = K.Q^T permuted-key trick;
// P trunc-packed in-register; l via ones-MFMA -> lands in the store lane/reg).
// CHK keys/chunk, NCH chunks, KM = key/row masking (s branch).
// ---------------------------------------------------------------------------
template<int CHK, int NCH, bool KM>
__device__ __forceinline__ void attn_core(
    const short* __restrict__ qg, const short* __restrict__ kg,
    const short* __restrict__ vtg, const int vstride, const int nreal,
    short* kl, short* vt, const int stid, const int snum,
    const int lane, const int qt0, const int nq,
    float* __restrict__ obase, const int ostride)
{
    const int c = lane & 15, gq = lane >> 4;
    const int VS = CHK + 8;

    // Q B-frag, scaled by 0.25*log2e, trunc-packed (g>=2 zero: d=16 < K=32)
    u4v qu = {0u, 0u, 0u, 0u};
    if (gq < 2) {
        const int qrow = KM ? min(qt0 + c, nq - 1) : (qt0 + c);
        const short* qr = qg + (size_t)qrow * 16 + 8 * gq;
        s8v raw = *(const s8v*)qr;
#pragma unroll
        for (int jp = 0; jp < 4; jp++)
            qu[jp] = tpack(bf2f(raw[2*jp+1]) * QSC, bf2f(raw[2*jp]) * QSC);
    }
    const s8v qf = __builtin_bit_cast(s8v, qu);

    s8v ones;
#pragma unroll
    for (int j = 0; j < 8; j++) ones[j] = (short)0x3F80;   // bf16 1.0

    f4 oacc = {0.f,0.f,0.f,0.f}, lacc = {0.f,0.f,0.f,0.f};
    const int krow_base = 8 * (c >> 2) + (c & 3);          // key permutation

    for (int ch = 0; ch < NCH; ch++) {
        const int kb0 = ch * CHK;
        __syncthreads();
        if (KM) {   // short-granular (vstride may be odd), zero-pad keys/rows
            for (int i = stid; i < CHK * 16 + 8; i += snum)
                kl[i] = (i < nreal * 16) ? kg[i] : (short)0;
            for (int i = stid; i < 16 * VS; i += snum) {
                int d = i / VS, col = i % VS;
                vt[i] = (col < nreal) ? vtg[(size_t)d * vstride + col] : (short)0;
            }
        } else {    // dword copies, contiguous
            const unsigned* kgd = (const unsigned*)(kg + (size_t)kb0 * 16);
            unsigned* kld = (unsigned*)kl;
            for (int i = stid; i < CHK * 8 + 4; i += snum)
                kld[i] = (i < CHK * 8) ? kgd[i] : 0u;      // +4 dw zero pad
            for (int i = stid; i < 16 * (CHK / 2); i += snum) {
                int d = i / (CHK / 2), cc = i % (CHK / 2);
                *(unsigned*)(vt + d * VS + 2 * cc) =
                    *(const unsigned*)(vtg + (size_t)d * vstride + kb0 + 2 * cc);
            }
        }
        __syncthreads();

#pragma unroll
        for (int st = 0; st < CHK / 32; st++) {
            const int kr0 = st * 32 + krow_base;
            s8v kf0 = *(const s8v*)(gq < 2 ? kl + kr0 * 16 + 8 * gq       : kl + CHK * 16);
            s8v kf1 = *(const s8v*)(gq < 2 ? kl + (kr0 + 4) * 16 + 8 * gq : kl + CHK * 16);
            s8v vf  = *(const s8v*)(vt + c * VS + st * 32 + 8 * gq);

            const f4 z = {0.f,0.f,0.f,0.f};
            f4 sa = __builtin_amdgcn_mfma_f32_16x16x32_bf16(kf0, qf, z, 0, 0, 0);
            f4 sb = __builtin_amdgcn_mfma_f32_16x16x32_bf16(kf1, qf, z, 0, 0, 0);

            float pa[4], pb[4];
#pragma unroll
            for (int r = 0; r < 4; r++) { pa[r] = EXP2(sa[r]); pb[r] = EXP2(sb[r]); }
            if (KM) {   // zero padded keys (key = 8*gq + j within the 32-step)
#pragma unroll
                for (int r = 0; r < 4; r++) {
                    if (kb0 + st*32 + 8*gq + r     >= nreal) pa[r] = 0.f;
                    if (kb0 + st*32 + 8*gq + 4 + r >= nreal) pb[r] = 0.f;
                }
            }
            u4v pu;
            pu[0] = tpack(pa[1], pa[0]); pu[1] = tpack(pa[3], pa[2]);
            pu[2] = tpack(pb[1], pb[0]); pu[3] = tpack(pb[3], pb[2]);
            s8v pf = __builtin_bit_cast(s8v, pu);

            oacc = __builtin_amdgcn_mfma_f32_16x16x32_bf16(pf, vf,   oacc, 0, 0, 0);
            lacc = __builtin_amdgcn_mfma_f32_16x16x32_bf16(pf, ones, lacc, 0, 0, 0);
        }
    }

#pragma unroll
    for (int r = 0; r < 4; r++) {       // lane (c,gq) reg r: O[q=qt0+4gq+r][dout=c]
        const int qrow = qt0 + 4 * gq + r;
        if (!KM || qrow < nq)
            obase[(size_t)qrow * ostride] = oacc[r] / lacc[r];
    }
}

// ---------------------------------------------------------------------------
// Kernel 2: ALL attention in one launch.
// blocks [0,1600): st | [1600,3200): t | [3200,5248): s (2 bh per block)
// ---------------------------------------------------------------------------
__global__ __launch_bounds__(256) void attn_all(
    const short* __restrict__ q0, const short* __restrict__ k0, const short* __restrict__ vt0,
    const short* __restrict__ q1, const short* __restrict__ k1, const short* __restrict__ vt1,
    const short* __restrict__ q2, const short* __restrict__ k2, const short* __restrict__ vt2,
    float* __restrict__ ob0, float* __restrict__ ob1, float* __restrict__ ob2)
{
    __shared__ short smem[5264];
    const int blk = blockIdx.x, tid = threadIdx.x;
    const int wave = tid >> 6, lane = tid & 63;
    const int c = lane & 15;

    if (blk < 1600) {                       // ---- st: N=1600, 10 x 160
        const int bh = blk / 25, b25 = blk % 25;
        const int qt0 = b25 * 64 + wave * 16;
        float* obase = ob2 + (size_t)(bh >> 3) * 1600 * 128 + (bh & 7) * 16 + c;
        attn_core<160, 10, false>(q2 + (size_t)bh * 25600, k2 + (size_t)bh * 25600,
                                  vt2 + (size_t)bh * 25600, 1600, 1600,
                                  smem, smem + 2568, tid, 256,
                                  lane, qt0, 1600, obase, 128);
    } else if (blk < 3200) {                // ---- t: N=64, single chunk
        const int bh = blk - 1600;
        float* obase = ob0 + (size_t)(bh >> 3) * 64 * 128 + (bh & 7) * 16 + c;
        attn_core<64, 1, false>(q0 + (size_t)bh * 1024, k0 + (size_t)bh * 1024,
                                vt0 + (size_t)bh * 1024, 64, 64,
                                smem, smem + 1040, tid, 256,
                                lane, wave * 16, 64, obase, 128);
    } else {                                // ---- s: N=25 (pad 32), 2 bh/block
        const int bs = blk - 3200;
        const int half = wave >> 1;
        const int bh = bs * 2 + half;
        const int qt0 = (wave & 1) * 16;
        short* kl = smem + half * 1160;     // 520 + 640 per region
        const int bat = bh >> 3, h = bh & 7;
        const int b2 = bat >> 6, t2 = bat & 63;
        float* obase = ob1 + ((size_t)b2 * 1600 + t2) * 128 + h * 16 + c;
        attn_core<32, 1, true>(q1 + (size_t)bh * 400, k1 + (size_t)bh * 400,
                               vt1 + (size_t)bh * 400, 25, 25,
                               kl, kl + 520, tid & 127, 128,
                               lane, qt0, 25, obase, 8192);
    }
}

// ---------------------------------------------------------------------------
// Kernel 3: output projection (MFMA, fused shuffle store) + identity copy.
// blocks [0,2400): proj (br = blk/800) | [2400,2600): id group
// ---------------------------------------------------------------------------
__global__ __launch_bounds__(256) void projid(
    const float* __restrict__ ob0, const float* __restrict__ ob1,
    const float* __restrict__ ob2, const short* __restrict__ wsw,
    const float* __restrict__ bp0, const float* __restrict__ bp1,
    const float* __restrict__ bp2,
    const float* __restrict__ x, float* __restrict__ out)
{
    __shared__ unsigned short xl[64 * 130];
    const int blk = blockIdx.x, tid = threadIdx.x;

    if (blk < 2400) {
        const int br = blk / 800, t8 = blk % 800;
        const float* obb = (br == 0) ? ob0 : (br == 1) ? ob1 : ob2;
        const float* bp  = (br == 0) ? bp0 : (br == 1) ? bp1 : bp2;
        const short* wswb = wsw + 147456 + br * 16384;
        const int grp = br + 1;
        const int tok0 = t8 * 16;
        const int wave = tid >> 6, lane = tid & 63;
        const int c = lane & 15, gq = lane >> 4;

        const float* arow = obb + (size_t)(tok0 + c) * 128 + 8 * gq;
        s8v af[4];
#pragma unroll
        for (int ks = 0; ks < 4; ks++) {
            float4 a = *(const float4*)(arow + ks * 32);
            float4 b = *(const float4*)(arow + ks * 32 + 4);
            af[ks][0]=f2bf(a.x); af[ks][1]=f2bf(a.y); af[ks][2]=f2bf(a.z); af[ks][3]=f2bf(a.w);
            af[ks][4]=f2bf(b.x); af[ks][5]=f2bf(b.y); af[ks][6]=f2bf(b.z); af[ks][7]=f2bf(b.w);
        }

        const int bn = t8 >> 2, b_ = bn / 25, n_ = bn % 25;
        const int t0 = (t8 & 3) * 16 + 4 * gq;

        for (int nti = 0; nti < 2; nti++) {
            const int nt = wave * 2 + nti;
            const short* bpw = wswb + ((size_t)(nt * 4) * 64 + lane) * 8;
            f4 acc = {0.f, 0.f, 0.f, 0.f};
#pragma unroll
            for (int ks = 0; ks < 4; ks++) {
                s8v bf = *(const s8v*)(bpw + ks * 512);
                acc = __builtin_amdgcn_mfma_f32_16x16x32_bf16(af[ks], bf, acc, 0, 0, 0);
            }
            const int c2 = nt * 16 + c;
            const float bv = bp[c2];
            float4 st = {acc[0]+bv, acc[1]+bv, acc[2]+bv, acc[3]+bv};
            *(float4*)(out + (size_t)b_ * 819200 + (size_t)(c2 * 4 + grp) * 1600
                           + n_ * 64 + t0) = st;
        }
    } else {
        const int bn = blk - 2400;
        const int b_ = bn / 25, n_ = bn % 25;
        for (int idx = tid; idx < 8192; idx += 256) {
            int row = idx >> 7, c2 = idx & 127;    // x is bf16-exact: trunc lossless
            xl[row * 130 + c2] =
                (unsigned short)(__float_as_uint(x[(size_t)(bn * 64 + row) * 512 + c2]) >> 16);
        }
        __syncthreads();
        const int t_ = tid & 63, cg = tid >> 6;
        const size_t base = (size_t)b_ * 819200 + (size_t)n_ * 64 + t_;
#pragma unroll
        for (int i = 0; i < 32; i++) {
            int c2 = cg + 4 * i;
            out[base + (size_t)(c2 * 4 + 0) * 1600] =
                __uint_as_float((unsigned)xl[t_ * 130 + c2] << 16);
        }
    }
}

// ---------------------------------------------------------------------------
extern "C" void kernel_launch(void* const* d_in, const int* in_sizes, int n_in,
                              void* d_out, int out_size, void* d_ws, size_t ws_size,
                              hipStream_t stream)
{
    const float* x        = (const float*)d_in[0];
    const float* t_wqkv   = (const float*)d_in[1];
    const float* t_bqkv   = (const float*)d_in[2];
    const float* t_wproj  = (const float*)d_in[3];
    const float* t_bproj  = (const float*)d_in[4];
    const float* s_wqkv   = (const float*)d_in[5];
    const float* s_bqkv   = (const float*)d_in[6];
    const float* s_wproj  = (const float*)d_in[7];
    const float* s_bproj  = (const float*)d_in[8];
    const float* st_wqkv  = (const float*)d_in[9];
    const float* st_bqkv  = (const float*)d_in[10];
    const float* st_wproj = (const float*)d_in[11];
    const float* st_bproj = (const float*)d_in[12];

    short* xbf = (short*)d_ws;              // 6,553,600 sh (13.1 MB)
    short* wsw = xbf + 6553600ull;          // 196,608 sh  (0.4 MB)
    short* qkv = wsw + 196608ull;           // 9 x BUF sh  (29.5 MB)
    short *q0 = qkv,           *k0 = qkv + BUF,     *vt0 = qkv + 2*BUF;
    short *q1 = qkv + 3*BUF,   *k1 = qkv + 4*BUF,   *vt1 = qkv + 5*BUF;
    short *q2 = qkv + 6*BUF,   *k2 = qkv + 7*BUF,   *vt2 = qkv + 8*BUF;
    float* ob0 = (float*)(qkv + 9*BUF);     // 3 x BUF fp32 (19.7 MB)
    float* ob1 = ob0 + BUF;
    float* ob2 = ob0 + 2*BUF;
    float* out = (float*)d_out;

    prep<<<3296, 256, 0, stream>>>(x, t_wqkv, s_wqkv, st_wqkv,
                                   t_wproj, s_wproj, st_wproj, xbf, wsw);
    qkv_all<<<2400, 256, 0, stream>>>(xbf, wsw, t_bqkv, s_bqkv, st_bqkv,
                                      q0, k0, vt0, q1, k1, vt1, q2, k2, vt2);
    attn_all<<<5248, 256, 0, stream>>>(q0, k0, vt0, q1, k1, vt1, q2, k2, vt2,
                                       ob0, ob1, ob2);
    projid<<<2600, 256, 0, stream>>>(ob0, ob1, ob2, wsw,
                                     t_bproj, s_bproj, st_bproj, x, out);
}